// Round 12
// baseline (149.733 us; speedup 1.0000x reference)
//
#include <hip/hip_runtime.h>
#include <hip/hip_bf16.h>
#include <math.h>

// Problem constants
#define BQ 128
#define PP 256
#define MQ 16
#define MP 32
#define DD 768
#define MROWS (BQ*MQ)   // 2048
#define NROWS (PP*MP)   // 8192

typedef float f32x4 __attribute__((ext_vector_type(4)));
typedef int   i32x4 __attribute__((ext_vector_type(4)));

// ---------- fp32 -> fp8 e4m3 + k-shuffle, both tensors, one launch ----------
// Within each 64-k block, 16B chunk c holds k-groups {c, c+4}. One
// ds_read_b128 feeds TWO 16x16x32 MFMAs (k and k+32). Also zero-inits
// loss_out[0] (stream-ordered before loss_kernel).
#define NQG (MROWS*96)   // 196608 groups of 8
#define NPG (NROWS*96)   // 786432

__global__ void conv_fp8_both(const float4* __restrict__ q, const float4* __restrict__ p,
                              unsigned char* __restrict__ qb, unsigned char* __restrict__ pb,
                              float* __restrict__ loss_out) {
    int idx = blockIdx.x * blockDim.x + threadIdx.x;
    if (idx == 0) loss_out[0] = 0.f;
    const float4* in; unsigned char* out; int i;
    if (idx < NQG) { in = q; out = qb; i = idx; }
    else           { in = p; out = pb; i = idx - NQG; }
    float4 x0 = in[2 * i];
    float4 x1 = in[2 * i + 1];
    int lo = 0, hi = 0;
    lo = __builtin_amdgcn_cvt_pk_fp8_f32(x0.x, x0.y, lo, false);
    lo = __builtin_amdgcn_cvt_pk_fp8_f32(x0.z, x0.w, lo, true);
    hi = __builtin_amdgcn_cvt_pk_fp8_f32(x1.x, x1.y, hi, false);
    hi = __builtin_amdgcn_cvt_pk_fp8_f32(x1.z, x1.w, hi, true);
    int row = i / 96;
    int g96 = i - row * 96;
    int blk = g96 >> 3, g = g96 & 7;
    int dstoff = (g < 4) ? (g * 16) : ((g - 4) * 16 + 8);
    *(uint2*)(out + (size_t)row * DD + blk * 64 + dstoff) = make_uint2((unsigned)lo, (unsigned)hi);
}

// ---------- DPP wave-64 reductions (pure VALU) ----------
__device__ inline int dpp_reduce_i32(int v) {
    v += __builtin_amdgcn_update_dpp(0, v, 0x111, 0xF, 0xF, true);  // row_shr:1
    v += __builtin_amdgcn_update_dpp(0, v, 0x112, 0xF, 0xF, true);  // row_shr:2
    v += __builtin_amdgcn_update_dpp(0, v, 0x114, 0xF, 0xF, true);  // row_shr:4
    v += __builtin_amdgcn_update_dpp(0, v, 0x118, 0xF, 0xF, true);  // row_shr:8
    v += __builtin_amdgcn_update_dpp(0, v, 0x142, 0xA, 0xF, true);  // row_bcast:15
    v += __builtin_amdgcn_update_dpp(0, v, 0x143, 0xC, 0xF, true);  // row_bcast:31
    return v;   // lane 63 = total
}

__device__ inline float dpp_reduce_f32(float x) {
    int m;
    m = __builtin_amdgcn_update_dpp(0, __float_as_int(x), 0x111, 0xF, 0xF, true); x += __int_as_float(m);
    m = __builtin_amdgcn_update_dpp(0, __float_as_int(x), 0x112, 0xF, 0xF, true); x += __int_as_float(m);
    m = __builtin_amdgcn_update_dpp(0, __float_as_int(x), 0x114, 0xF, 0xF, true); x += __int_as_float(m);
    m = __builtin_amdgcn_update_dpp(0, __float_as_int(x), 0x118, 0xF, 0xF, true); x += __int_as_float(m);
    m = __builtin_amdgcn_update_dpp(0, __float_as_int(x), 0x142, 0xA, 0xF, true); x += __int_as_float(m);
    m = __builtin_amdgcn_update_dpp(0, __float_as_int(x), 0x143, 0xC, 0xF, true); x += __int_as_float(m);
    return x;   // lane 63 = total
}

// ---------- fused fp8 GEMM (64x128, ring-2, one barrier/iter) + select ------
// R12: single-variable change from R11 — occupancy. R11: ring-3 36 KB LDS
// caps 4 blocks/CU = 16 waves (Occ 35%); select phase (no LDS use!) is
// latency-bound on 10-serial-step descents with only ~2.8 waves/SIMD to
// hide it. Evidence: R1's 61%-occ kernel matched R11 DESPITE 10.6 MB spill
// traffic. Untested cell: high occupancy + no spills + pipelined loop.
//  - ring-2 (2 x 12 KB = 24 KB) -> 6 blocks/CU = 24 waves/CU (75% cap).
//  - (256,6): 85-reg budget; est. need 52 arch + 32 acc = 84. WRITE_SIZE
//    is the spill tripwire (>=2 MB -> revert to (256,4)).
//  - wait vmcnt(0) each iter: ring-2's only outstanding group is tile t's
//    own 3 loads, issued ONE FULL ITERATION earlier (~200+ cyc of
//    ds_read+MFMA cover). One barrier per iter; stage(t+1) goes into the
//    disjoint slot right after the barrier (same safety proof as R9).
// Select phase byte-identical to R11 -> absmax must stay exactly 96.0.
#define BM 64
#define BN 128
#define BK 64
#define KIT (DD / BK)    // 12
#define SLOT 12288       // A 4 KB + B 8 KB

__device__ inline void load16_to_lds(const unsigned char* g, unsigned char* l) {
    __builtin_amdgcn_global_load_lds(
        (const __attribute__((address_space(1))) unsigned int*)(g),
        (__attribute__((address_space(3))) unsigned int*)(l),
        16, 0, 0);
}

__device__ inline unsigned lds_off(const unsigned char* p) {
    return (unsigned)(unsigned long long)
        (const __attribute__((address_space(3))) unsigned char*)p;
}

__device__ inline i32x4 ds_read_b128a(unsigned addr) {
    i32x4 d;
    asm volatile("ds_read_b128 %0, %1" : "=v"(d) : "v"(addr));
    return d;
}

__device__ inline float softplus_f(float x) {
    return (x > 20.f) ? x : log1pf(expf(x));
}

__device__ inline long lo64(i32x4 v) {
    return (long)(((unsigned long)(unsigned)v[1] << 32) | (unsigned)v[0]);
}
__device__ inline long hi64(i32x4 v) {
    return (long)(((unsigned long)(unsigned)v[3] << 32) | (unsigned)v[2]);
}

__global__ __launch_bounds__(256, 6) void gemm_select(const unsigned char* __restrict__ A,
                                                      const unsigned char* __restrict__ B,
                                                      const int* __restrict__ qm,
                                                      const int* __restrict__ pm,
                                                      const float* __restrict__ araw,
                                                      const float* __restrict__ braw,
                                                      float* __restrict__ logits) {
    __shared__ __align__(16) unsigned char smem[2 * SLOT];   // 24 KB ring-2

    const int tid  = threadIdx.x;
    const int lane = tid & 63;
    const int wid  = tid >> 6;        // 4 waves, 2x2 over 64x128
    const int wr   = wid >> 1;
    const int wc   = wid & 1;
    const int tileM = blockIdx.y * BM;
    const int tileN = blockIdx.x * BN;
    const int bBase = blockIdx.y * 4;
    const int pBase = blockIdx.x * 4;

    // ---- GEMM phase (fp8, BK=64, ring-2 one-barrier pipeline)
    f32x4 acc[2][4];
    #pragma unroll
    for (int i = 0; i < 2; ++i)
        #pragma unroll
        for (int j = 0; j < 4; ++j) {
            f32x4 z = {0.f, 0.f, 0.f, 0.f};
            acc[i][j] = z;
        }

    const int lr = lane >> 2, l2 = lane & 3;
    const int sg = (lr >> 1) & 3;                    // sigma(row): row%16 = lr
    const int rowA  = wid * 16 + lr;                 // A rows 0..63
    const int rowB0 = wid * 16 + lr;                 // B rows 0..63
    const int rowB1 = 64 + wid * 16 + lr;            // B rows 64..127
    const unsigned char* pa  = A + (size_t)(tileM + rowA ) * DD + ((l2 ^ sg) << 4);
    const unsigned char* pb0 = B + (size_t)(tileN + rowB0) * DD + ((l2 ^ sg) << 4);
    const unsigned char* pb1 = B + (size_t)(tileN + rowB1) * DD + ((l2 ^ sg) << 4);
    const int dA  = wid * 16 * BK;                   // wave-uniform, A region
    const int dB0 = 4096 + wid * 16 * BK;            // B region base 4096
    const int dB1 = 4096 + (4 + wid) * 16 * BK;

    const int r0 = lane & 15;
    const int q  = lane >> 4;
    const int slotq = ((q ^ ((r0 >> 1) & 3)) << 4);
    const int abase = (wr * 32 + r0) * BK + slotq;          // + mi*16*BK
    const int bbase = 4096 + (wc * 64 + r0) * BK + slotq;   // + ni*16*BK
    const unsigned lds0 = lds_off(smem);

    // prologue: stage K-tile 0 into slot 0 (3 loads outstanding)
    load16_to_lds(pa,  smem + dA);
    load16_to_lds(pb0, smem + dB0);
    load16_to_lds(pb1, smem + dB1);
    pa += BK; pb0 += BK; pb1 += BK;

    #pragma unroll
    for (int t = 0; t < KIT; ++t) {
        // tile t's 3 loads were issued one full iteration ago; drain them.
        asm volatile("s_waitcnt vmcnt(0)" ::: "memory");
        __builtin_amdgcn_s_barrier();   // t's data visible; t-1 reads done

        if (t + 1 < KIT) {   // stage t+1 into the slot t-1 just vacated
            unsigned char* sb = smem + ((t + 1) & 1) * SLOT;
            load16_to_lds(pa,  sb + dA);
            load16_to_lds(pb0, sb + dB0);
            load16_to_lds(pb1, sb + dB1);
            pa += BK; pb0 += BK; pb1 += BK;
        }

        const unsigned sb = lds0 + (unsigned)((t & 1) * SLOT);
        i32x4 a0 = ds_read_b128a(sb + abase);
        i32x4 a1 = ds_read_b128a(sb + abase + 16 * BK);
        i32x4 b0 = ds_read_b128a(sb + bbase);
        i32x4 b1 = ds_read_b128a(sb + bbase + 16 * BK);
        i32x4 b2 = ds_read_b128a(sb + bbase + 32 * BK);
        i32x4 b3 = ds_read_b128a(sb + bbase + 48 * BK);
        asm volatile("s_waitcnt lgkmcnt(0)" ::: "memory");
        __builtin_amdgcn_sched_barrier(0);   // rule #18: pin MFMAs below wait

        acc[0][0] = __builtin_amdgcn_mfma_f32_16x16x32_fp8_fp8(lo64(a0), lo64(b0), acc[0][0], 0, 0, 0);
        acc[0][1] = __builtin_amdgcn_mfma_f32_16x16x32_fp8_fp8(lo64(a0), lo64(b1), acc[0][1], 0, 0, 0);
        acc[0][2] = __builtin_amdgcn_mfma_f32_16x16x32_fp8_fp8(lo64(a0), lo64(b2), acc[0][2], 0, 0, 0);
        acc[0][3] = __builtin_amdgcn_mfma_f32_16x16x32_fp8_fp8(lo64(a0), lo64(b3), acc[0][3], 0, 0, 0);
        acc[1][0] = __builtin_amdgcn_mfma_f32_16x16x32_fp8_fp8(lo64(a1), lo64(b0), acc[1][0], 0, 0, 0);
        acc[1][1] = __builtin_amdgcn_mfma_f32_16x16x32_fp8_fp8(lo64(a1), lo64(b1), acc[1][1], 0, 0, 0);
        acc[1][2] = __builtin_amdgcn_mfma_f32_16x16x32_fp8_fp8(lo64(a1), lo64(b2), acc[1][2], 0, 0, 0);
        acc[1][3] = __builtin_amdgcn_mfma_f32_16x16x32_fp8_fp8(lo64(a1), lo64(b3), acc[1][3], 0, 0, 0);
        acc[0][0] = __builtin_amdgcn_mfma_f32_16x16x32_fp8_fp8(hi64(a0), hi64(b0), acc[0][0], 0, 0, 0);
        acc[0][1] = __builtin_amdgcn_mfma_f32_16x16x32_fp8_fp8(hi64(a0), hi64(b1), acc[0][1], 0, 0, 0);
        acc[0][2] = __builtin_amdgcn_mfma_f32_16x16x32_fp8_fp8(hi64(a0), hi64(b2), acc[0][2], 0, 0, 0);
        acc[0][3] = __builtin_amdgcn_mfma_f32_16x16x32_fp8_fp8(hi64(a0), hi64(b3), acc[0][3], 0, 0, 0);
        acc[1][0] = __builtin_amdgcn_mfma_f32_16x16x32_fp8_fp8(hi64(a1), hi64(b0), acc[1][0], 0, 0, 0);
        acc[1][1] = __builtin_amdgcn_mfma_f32_16x16x32_fp8_fp8(hi64(a1), hi64(b1), acc[1][1], 0, 0, 0);
        acc[1][2] = __builtin_amdgcn_mfma_f32_16x16x32_fp8_fp8(hi64(a1), hi64(b2), acc[1][2], 0, 0, 0);
        acc[1][3] = __builtin_amdgcn_mfma_f32_16x16x32_fp8_fp8(hi64(a1), hi64(b3), acc[1][3], 0, 0, 0);
    }

    // ---- per-wave mask words (after K-loop: not live across it)
    unsigned qw[2]; int nq[2];
    #pragma unroll
    for (int t = 0; t < 2; ++t) {
        bool v = (lane < MQ) && (qm[(bBase + wr * 2 + t) * MQ + lane] != 0);
        unsigned long long bal = __ballot(v);
        qw[t] = (unsigned)bal;
        nq[t] = __popcll(bal);
    }
    unsigned pw[2]; int np_[2];
    #pragma unroll
    for (int t = 0; t < 2; ++t) {
        bool v = (lane < MP) && (pm[(pBase + wc * 2 + t) * MP + lane] != 0);
        unsigned long long bal = __ballot(v);
        pw[t] = (unsigned)bal;
        np_[t] = __popcll(bal);
    }

    // ---- selection: 4 pairs/wave; SALU/VALU-balanced dual formulations
    // C/D layout (m89): row=(lane>>4)*4+(t&3), col=(t>>2)*16+(lane&15)
    float aco = softplus_f(araw[0]);
    float bco = softplus_f(braw[0]);
    const int rowb = (lane >> 4) * 4;
    const int colb = lane & 15;

    // per-lane validity precompute
    const int rown0 = (int)((qw[0] >> rowb) & 0xFu);
    const int rown1 = (int)((qw[1] >> rowb) & 0xFu);
    const int cb00 = (int)((pw[0] >> colb) & 1u);
    const int cb01 = (int)((pw[0] >> (colb + 16)) & 1u);
    const int cb10 = (int)((pw[1] >> colb) & 1u);
    const int cb11 = (int)((pw[1] >> (colb + 16)) & 1u);

    #pragma unroll 1
    for (int pair = 0; pair < 4; ++pair) {
        f32x4 w0, w1; int vm8, nqv, npv;
        switch (pair) {   // static acc indexing (rule #20: no runtime index)
        case 0:  w0 = acc[0][0]; w1 = acc[0][1]; vm8 = (cb00 ? rown0 : 0) | (cb01 ? (rown0 << 4) : 0); nqv = nq[0]; npv = np_[0]; break;
        case 1:  w0 = acc[0][2]; w1 = acc[0][3]; vm8 = (cb10 ? rown0 : 0) | (cb11 ? (rown0 << 4) : 0); nqv = nq[0]; npv = np_[1]; break;
        case 2:  w0 = acc[1][0]; w1 = acc[1][1]; vm8 = (cb00 ? rown1 : 0) | (cb01 ? (rown1 << 4) : 0); nqv = nq[1]; npv = np_[0]; break;
        default: w0 = acc[1][2]; w1 = acc[1][3]; vm8 = (cb10 ? rown1 : 0) | (cb11 ? (rown1 << 4) : 0); nqv = nq[1]; npv = np_[1]; break;
        }

        int n  = nqv * npv;               // >= 1
        int k  = (4 * n) / 10; if (k < 1) k = 1;
        int m2 = n - (8 * n) / 10;        // complement rank, >= 1

        float v[8] = {w0[0], w0[1], w0[2], w0[3], w1[0], w1[1], w1[2], w1[3]};
        int key[8];
        float tot = 0.f;
        #pragma unroll
        for (int t = 0; t < 8; ++t) {
            int kf = (int)floorf(v[t] * 2.0f) + 512;     // monotone, |v| << 256
            kf = min(max(kf, 1), 1023);                  // v_med3_i32
            int msk = (vm8 << (31 - t)) >> 31;           // -1 if valid, else 0
            key[t] = kf & msk;                           // valid >= 1
            tot += __int_as_float(__float_as_int(v[t]) & msk);   // +0.0 if invalid
        }

        // dual 10-bit MSB-first radix descent — two formulations to balance
        // the shared SALU (ballot path) against the VALU/DPP path.
        int T1 = 0, T2 = 0;
        if ((pair & 1) == 0) {
            // ballot -> s_bcnt1_b64 (SALU); c1==c2 prefix shares counts
            for (int bit = 9; bit >= 0; --bit) {
                int c1 = T1 | (1 << bit);
                int c2 = T2 | (1 << bit);
                int cnt1 = 0;
                #pragma unroll
                for (int t = 0; t < 8; ++t)
                    cnt1 += __popcll(__ballot(key[t] >= c1));
                int cnt2;
                if (c2 == c1) {
                    cnt2 = cnt1;   // wave-uniform skip (identical count)
                } else {
                    cnt2 = 0;
                    #pragma unroll
                    for (int t = 0; t < 8; ++t)
                        cnt2 += __popcll(__ballot(key[t] >= c2));
                }
                if (cnt1 >= k)  T1 = c1;
                if (cnt2 >= m2) T2 = c2;
            }
        } else {
            // packed per-lane counts + DPP reduce + readlane (VALU pipe)
            for (int bit = 9; bit >= 0; --bit) {
                int c1 = T1 | (1 << bit);
                int c2 = T2 | (1 << bit);
                int cnt = 0;
                #pragma unroll
                for (int t = 0; t < 8; ++t) {
                    cnt += (key[t] >= c1) ? 1 : 0;
                    cnt += (key[t] >= c2) ? 0x10000 : 0;
                }
                cnt = dpp_reduce_i32(cnt);
                unsigned total = (unsigned)__builtin_amdgcn_readlane(cnt, 63);
                if ((int)(total & 0xFFFFu) >= k)  T1 = c1;
                if ((int)(total >> 16)    >= m2) T2 = c2;
            }
        }

        // tie-corrected sums (same formulation split for the counts)
        float S1 = 0.f, S2 = 0.f;
        int c1n, c2n;
        if ((pair & 1) == 0) {
            c1n = 0; c2n = 0;
            #pragma unroll
            for (int t = 0; t < 8; ++t) {
                bool g1 = key[t] > T1;
                bool g2 = key[t] > T2;
                if (g1) S1 += v[t];
                if (g2) S2 += v[t];
                c1n += __popcll(__ballot(g1));
                c2n += __popcll(__ballot(g2));
            }
        } else {
            int pc = 0;
            #pragma unroll
            for (int t = 0; t < 8; ++t) {
                if (key[t] > T1) { S1 += v[t]; pc += 1; }
                if (key[t] > T2) { S2 += v[t]; pc += 0x10000; }
            }
            pc = dpp_reduce_i32(pc);
            pc = __builtin_amdgcn_readlane(pc, 63);
            c1n = pc & 0xFFFF;
            c2n = (int)(((unsigned)pc) >> 16);
        }
        S1  = dpp_reduce_f32(S1);
        S2  = dpp_reduce_f32(S2);
        tot = dpp_reduce_f32(tot);

        if (lane == 63) {
            float f1 = 0.5f * (float)(T1 - 512);   // tie-bucket lower edge
            float f2 = 0.5f * (float)(T2 - 512);
            float top = S1 + (float)(k  - c1n) * f1;
            float cmp = S2 + (float)(m2 - c2n) * f2;
            float bot = tot - cmp;
            int bl = pair >> 1, pl = pair & 1;
            logits[(bBase + wr * 2 + bl) * PP + (pBase + wc * 2 + pl)] = aco * top - bco * bot;
        }
    }
}

// ---------- loss = mean_b (lse(logits[b,:]) - logits[b,b]) ----------
// 32 blocks x 4 waves, one row per wave, atomicAdd partials (out[0] zeroed
// by conv_fp8_both, stream-ordered).
__global__ __launch_bounds__(256) void loss_kernel(const float* __restrict__ logits,
                                                   float* __restrict__ loss_out) {
    const int lane = threadIdx.x & 63;
    const int wid  = threadIdx.x >> 6;
    const int r = blockIdx.x * 4 + wid;
    const float* row = logits + r * PP;
    float x0 = row[lane], x1 = row[lane + 64], x2 = row[lane + 128], x3 = row[lane + 192];
    float m = fmaxf(fmaxf(x0, x1), fmaxf(x2, x3));
    #pragma unroll
    for (int off = 32; off > 0; off >>= 1)
        m = fmaxf(m, __shfl_xor(m, off, 64));
    float s = expf(x0 - m) + expf(x1 - m) + expf(x2 - m) + expf(x3 - m);
    #pragma unroll
    for (int off = 32; off > 0; off >>= 1)
        s += __shfl_xor(s, off, 64);
    if (lane == 0)
        atomicAdd(loss_out, (m + logf(s) - row[r]) * (1.0f / (float)BQ));
}

extern "C" void kernel_launch(void* const* d_in, const int* in_sizes, int n_in,
                              void* d_out, int out_size, void* d_ws, size_t ws_size,
                              hipStream_t stream) {
    const float* q  = (const float*)d_in[0];
    const float* pe = (const float*)d_in[1];
    const int*   qm = (const int*)d_in[2];
    const int*   pm = (const int*)d_in[3];
    const float* ar = (const float*)d_in[4];
    const float* br = (const float*)d_in[5];
    float* out = (float*)d_out;           // [0] = loss, [1..32768] = logits

    // workspace: qb (1.5 MB fp8, k-shuffled) | pb (6 MB fp8, k-shuffled)
    char* ws = (char*)d_ws;
    unsigned char* qb = (unsigned char*)ws;
    unsigned char* pb = (unsigned char*)(ws + (size_t)MROWS * DD);

    // 1) convert fp32 -> fp8 e4m3 with k-shuffle (+ zero loss accumulator)
    conv_fp8_both<<<(NQG + NPG) / 256, 256, 0, stream>>>(
        (const float4*)q, (const float4*)pe, qb, pb, out);

    // 2) fused fp8 sim-GEMM + dual top-k -> logits
    // 24 KB ring-2 LDS; (256,6) -> 6 blocks/CU = 24 waves/CU, no spills
    dim3 gg(NROWS / BN, MROWS / BM, 1);   // (64, 32) = 2048 blocks
    gemm_select<<<gg, 256, 0, stream>>>(qb, pb, qm, pm, ar, br, out + 1);

    // 3) loss (parallel, atomic accumulate)
    loss_kernel<<<32, 256, 0, stream>>>(out + 1, out);
}

// Round 13
// 135.159 us; speedup vs baseline: 1.1078x; 1.1078x over previous
//
#include <hip/hip_runtime.h>
#include <hip/hip_bf16.h>
#include <math.h>

// Problem constants
#define BQ 128
#define PP 256
#define MQ 16
#define MP 32
#define DD 768
#define MROWS (BQ*MQ)   // 2048
#define NROWS (PP*MP)   // 8192

typedef float f32x4 __attribute__((ext_vector_type(4)));
typedef int   i32x4 __attribute__((ext_vector_type(4)));

// ---------- fp32 -> fp8 e4m3 + k-shuffle, both tensors, one launch ----------
// Within each 64-k block, 16B chunk c holds k-groups {c, c+4}. One
// ds_read_b128 feeds TWO 16x16x32 MFMAs (k and k+32). Also zero-inits
// loss_out[0] (stream-ordered before loss_kernel).
#define NQG (MROWS*96)   // 196608 groups of 8
#define NPG (NROWS*96)   // 786432

__global__ void conv_fp8_both(const float4* __restrict__ q, const float4* __restrict__ p,
                              unsigned char* __restrict__ qb, unsigned char* __restrict__ pb,
                              float* __restrict__ loss_out) {
    int idx = blockIdx.x * blockDim.x + threadIdx.x;
    if (idx == 0) loss_out[0] = 0.f;
    const float4* in; unsigned char* out; int i;
    if (idx < NQG) { in = q; out = qb; i = idx; }
    else           { in = p; out = pb; i = idx - NQG; }
    float4 x0 = in[2 * i];
    float4 x1 = in[2 * i + 1];
    int lo = 0, hi = 0;
    lo = __builtin_amdgcn_cvt_pk_fp8_f32(x0.x, x0.y, lo, false);
    lo = __builtin_amdgcn_cvt_pk_fp8_f32(x0.z, x0.w, lo, true);
    hi = __builtin_amdgcn_cvt_pk_fp8_f32(x1.x, x1.y, hi, false);
    hi = __builtin_amdgcn_cvt_pk_fp8_f32(x1.z, x1.w, hi, true);
    int row = i / 96;
    int g96 = i - row * 96;
    int blk = g96 >> 3, g = g96 & 7;
    int dstoff = (g < 4) ? (g * 16) : ((g - 4) * 16 + 8);
    *(uint2*)(out + (size_t)row * DD + blk * 64 + dstoff) = make_uint2((unsigned)lo, (unsigned)hi);
}

// ---------- DPP wave-64 reductions (pure VALU) ----------
__device__ inline int dpp_reduce_i32(int v) {
    v += __builtin_amdgcn_update_dpp(0, v, 0x111, 0xF, 0xF, true);  // row_shr:1
    v += __builtin_amdgcn_update_dpp(0, v, 0x112, 0xF, 0xF, true);  // row_shr:2
    v += __builtin_amdgcn_update_dpp(0, v, 0x114, 0xF, 0xF, true);  // row_shr:4
    v += __builtin_amdgcn_update_dpp(0, v, 0x118, 0xF, 0xF, true);  // row_shr:8
    v += __builtin_amdgcn_update_dpp(0, v, 0x142, 0xA, 0xF, true);  // row_bcast:15
    v += __builtin_amdgcn_update_dpp(0, v, 0x143, 0xC, 0xF, true);  // row_bcast:31
    return v;   // lane 63 = total
}

__device__ inline float dpp_reduce_f32(float x) {
    int m;
    m = __builtin_amdgcn_update_dpp(0, __float_as_int(x), 0x111, 0xF, 0xF, true); x += __int_as_float(m);
    m = __builtin_amdgcn_update_dpp(0, __float_as_int(x), 0x112, 0xF, 0xF, true); x += __int_as_float(m);
    m = __builtin_amdgcn_update_dpp(0, __float_as_int(x), 0x114, 0xF, 0xF, true); x += __int_as_float(m);
    m = __builtin_amdgcn_update_dpp(0, __float_as_int(x), 0x118, 0xF, 0xF, true); x += __int_as_float(m);
    m = __builtin_amdgcn_update_dpp(0, __float_as_int(x), 0x142, 0xA, 0xF, true); x += __int_as_float(m);
    m = __builtin_amdgcn_update_dpp(0, __float_as_int(x), 0x143, 0xC, 0xF, true); x += __int_as_float(m);
    return x;   // lane 63 = total
}

// ---------- fused fp8 GEMM (64x128, ring-3, counted vmcnt) + select ---------
// R13: GEMM reverted to R11 exactly (53.9 us best; R12's (256,6) spilled —
// 35 MB scratch — tripwire fired, cell unreachable). Single-variable change:
// the select pair loop is FULLY UNROLLED. R11's 4 descents ran sequentially
// (#pragma unroll 1): 4 x 10 dependent cross-lane reduces (~50-100 cyc
// latency each) with only ~2.8 waves/SIMD to hide them. The 4 pairs are
// mutually independent -> unrolled, the scheduler interleaves 4 chains (ILP)
// and the ballot(SALU)/DPP(VALU) split interleaves across pipes per step.
// Liveness: acc 32 + key 32 + state ~= 100 arch, fits (256,4)'s 128 budget.
// WRITE_SIZE >= 2 MB = spilled -> experiment void. Arithmetic order per pair
// unchanged -> absmax must stay exactly 96.0.
#define BM 64
#define BN 128
#define BK 64
#define KIT (DD / BK)    // 12
#define SLOT 12288       // A 4 KB + B 8 KB

__device__ inline void load16_to_lds(const unsigned char* g, unsigned char* l) {
    __builtin_amdgcn_global_load_lds(
        (const __attribute__((address_space(1))) unsigned int*)(g),
        (__attribute__((address_space(3))) unsigned int*)(l),
        16, 0, 0);
}

__device__ inline unsigned lds_off(const unsigned char* p) {
    return (unsigned)(unsigned long long)
        (const __attribute__((address_space(3))) unsigned char*)p;
}

__device__ inline i32x4 ds_read_b128a(unsigned addr) {
    i32x4 d;
    asm volatile("ds_read_b128 %0, %1" : "=v"(d) : "v"(addr));
    return d;
}

__device__ inline float softplus_f(float x) {
    return (x > 20.f) ? x : log1pf(expf(x));
}

__device__ inline long lo64(i32x4 v) {
    return (long)(((unsigned long)(unsigned)v[1] << 32) | (unsigned)v[0]);
}
__device__ inline long hi64(i32x4 v) {
    return (long)(((unsigned long)(unsigned)v[3] << 32) | (unsigned)v[2]);
}

__global__ __launch_bounds__(256, 4) void gemm_select(const unsigned char* __restrict__ A,
                                                      const unsigned char* __restrict__ B,
                                                      const int* __restrict__ qm,
                                                      const int* __restrict__ pm,
                                                      const float* __restrict__ araw,
                                                      const float* __restrict__ braw,
                                                      float* __restrict__ logits) {
    __shared__ __align__(16) unsigned char smem[3 * SLOT];   // 36 KB ring

    const int tid  = threadIdx.x;
    const int lane = tid & 63;
    const int wid  = tid >> 6;        // 4 waves, 2x2 over 64x128
    const int wr   = wid >> 1;
    const int wc   = wid & 1;
    const int tileM = blockIdx.y * BM;
    const int tileN = blockIdx.x * BN;
    const int bBase = blockIdx.y * 4;
    const int pBase = blockIdx.x * 4;

    // ---- GEMM phase (fp8, BK=64, ring-3 counted-vmcnt pipeline) — R11 verbatim
    f32x4 acc[2][4];
    #pragma unroll
    for (int i = 0; i < 2; ++i)
        #pragma unroll
        for (int j = 0; j < 4; ++j) {
            f32x4 z = {0.f, 0.f, 0.f, 0.f};
            acc[i][j] = z;
        }

    const int lr = lane >> 2, l2 = lane & 3;
    const int sg = (lr >> 1) & 3;                    // sigma(row): row%16 = lr
    const int rowA  = wid * 16 + lr;                 // A rows 0..63
    const int rowB0 = wid * 16 + lr;                 // B rows 0..63
    const int rowB1 = 64 + wid * 16 + lr;            // B rows 64..127
    const unsigned char* pa  = A + (size_t)(tileM + rowA ) * DD + ((l2 ^ sg) << 4);
    const unsigned char* pb0 = B + (size_t)(tileN + rowB0) * DD + ((l2 ^ sg) << 4);
    const unsigned char* pb1 = B + (size_t)(tileN + rowB1) * DD + ((l2 ^ sg) << 4);
    const int dA  = wid * 16 * BK;                   // wave-uniform, A region
    const int dB0 = 4096 + wid * 16 * BK;            // B region base 4096
    const int dB1 = 4096 + (4 + wid) * 16 * BK;

    const int r0 = lane & 15;
    const int q  = lane >> 4;
    const int slotq = ((q ^ ((r0 >> 1) & 3)) << 4);
    const int abase = (wr * 32 + r0) * BK + slotq;          // + mi*16*BK
    const int bbase = 4096 + (wc * 64 + r0) * BK + slotq;   // + ni*16*BK
    const unsigned lds0 = lds_off(smem);

    // prologue: stage K-tiles 0,1 into slots 0,1 (6 loads outstanding)
    #pragma unroll
    for (int t = 0; t < 2; ++t) {
        unsigned char* sb = smem + t * SLOT;
        load16_to_lds(pa,  sb + dA);
        load16_to_lds(pb0, sb + dB0);
        load16_to_lds(pb1, sb + dB1);
        pa += BK; pb0 += BK; pb1 += BK;
    }

    #pragma unroll
    for (int t = 0; t < KIT; ++t) {
        if (t == 0 || t == KIT - 1) asm volatile("s_waitcnt vmcnt(0)" ::: "memory");
        else                        asm volatile("s_waitcnt vmcnt(3)" ::: "memory");
        __builtin_amdgcn_s_barrier();   // t's data visible; t-1 reads done

        if (t + 2 < KIT) {   // stage t+2 into slot (t+2)%3 (= slot of t-1)
            unsigned char* sb = smem + ((t + 2) % 3) * SLOT;
            load16_to_lds(pa,  sb + dA);
            load16_to_lds(pb0, sb + dB0);
            load16_to_lds(pb1, sb + dB1);
            pa += BK; pb0 += BK; pb1 += BK;
        }

        const unsigned sb = lds0 + (unsigned)((t % 3) * SLOT);
        i32x4 a0 = ds_read_b128a(sb + abase);
        i32x4 a1 = ds_read_b128a(sb + abase + 16 * BK);
        i32x4 b0 = ds_read_b128a(sb + bbase);
        i32x4 b1 = ds_read_b128a(sb + bbase + 16 * BK);
        i32x4 b2 = ds_read_b128a(sb + bbase + 32 * BK);
        i32x4 b3 = ds_read_b128a(sb + bbase + 48 * BK);
        asm volatile("s_waitcnt lgkmcnt(0)" ::: "memory");
        __builtin_amdgcn_sched_barrier(0);   // rule #18: pin MFMAs below wait

        acc[0][0] = __builtin_amdgcn_mfma_f32_16x16x32_fp8_fp8(lo64(a0), lo64(b0), acc[0][0], 0, 0, 0);
        acc[0][1] = __builtin_amdgcn_mfma_f32_16x16x32_fp8_fp8(lo64(a0), lo64(b1), acc[0][1], 0, 0, 0);
        acc[0][2] = __builtin_amdgcn_mfma_f32_16x16x32_fp8_fp8(lo64(a0), lo64(b2), acc[0][2], 0, 0, 0);
        acc[0][3] = __builtin_amdgcn_mfma_f32_16x16x32_fp8_fp8(lo64(a0), lo64(b3), acc[0][3], 0, 0, 0);
        acc[1][0] = __builtin_amdgcn_mfma_f32_16x16x32_fp8_fp8(lo64(a1), lo64(b0), acc[1][0], 0, 0, 0);
        acc[1][1] = __builtin_amdgcn_mfma_f32_16x16x32_fp8_fp8(lo64(a1), lo64(b1), acc[1][1], 0, 0, 0);
        acc[1][2] = __builtin_amdgcn_mfma_f32_16x16x32_fp8_fp8(lo64(a1), lo64(b2), acc[1][2], 0, 0, 0);
        acc[1][3] = __builtin_amdgcn_mfma_f32_16x16x32_fp8_fp8(lo64(a1), lo64(b3), acc[1][3], 0, 0, 0);
        acc[0][0] = __builtin_amdgcn_mfma_f32_16x16x32_fp8_fp8(hi64(a0), hi64(b0), acc[0][0], 0, 0, 0);
        acc[0][1] = __builtin_amdgcn_mfma_f32_16x16x32_fp8_fp8(hi64(a0), hi64(b1), acc[0][1], 0, 0, 0);
        acc[0][2] = __builtin_amdgcn_mfma_f32_16x16x32_fp8_fp8(hi64(a0), hi64(b2), acc[0][2], 0, 0, 0);
        acc[0][3] = __builtin_amdgcn_mfma_f32_16x16x32_fp8_fp8(hi64(a0), hi64(b3), acc[0][3], 0, 0, 0);
        acc[1][0] = __builtin_amdgcn_mfma_f32_16x16x32_fp8_fp8(hi64(a1), hi64(b0), acc[1][0], 0, 0, 0);
        acc[1][1] = __builtin_amdgcn_mfma_f32_16x16x32_fp8_fp8(hi64(a1), hi64(b1), acc[1][1], 0, 0, 0);
        acc[1][2] = __builtin_amdgcn_mfma_f32_16x16x32_fp8_fp8(hi64(a1), hi64(b2), acc[1][2], 0, 0, 0);
        acc[1][3] = __builtin_amdgcn_mfma_f32_16x16x32_fp8_fp8(hi64(a1), hi64(b3), acc[1][3], 0, 0, 0);
    }

    // ---- per-wave mask words (after K-loop: not live across it)
    unsigned qw[2]; int nq[2];
    #pragma unroll
    for (int t = 0; t < 2; ++t) {
        bool v = (lane < MQ) && (qm[(bBase + wr * 2 + t) * MQ + lane] != 0);
        unsigned long long bal = __ballot(v);
        qw[t] = (unsigned)bal;
        nq[t] = __popcll(bal);
    }
    unsigned pw[2]; int np_[2];
    #pragma unroll
    for (int t = 0; t < 2; ++t) {
        bool v = (lane < MP) && (pm[(pBase + wc * 2 + t) * MP + lane] != 0);
        unsigned long long bal = __ballot(v);
        pw[t] = (unsigned)bal;
        np_[t] = __popcll(bal);
    }

    // ---- selection: 4 pairs/wave, FULLY UNROLLED (4 independent descents
    // interleaved by the scheduler: ILP hides the per-step reduce latency)
    // C/D layout (m89): row=(lane>>4)*4+(t&3), col=(t>>2)*16+(lane&15)
    float aco = softplus_f(araw[0]);
    float bco = softplus_f(braw[0]);
    const int rowb = (lane >> 4) * 4;
    const int colb = lane & 15;

    // per-lane validity precompute
    const int rown0 = (int)((qw[0] >> rowb) & 0xFu);
    const int rown1 = (int)((qw[1] >> rowb) & 0xFu);
    const int cb00 = (int)((pw[0] >> colb) & 1u);
    const int cb01 = (int)((pw[0] >> (colb + 16)) & 1u);
    const int cb10 = (int)((pw[1] >> colb) & 1u);
    const int cb11 = (int)((pw[1] >> (colb + 16)) & 1u);

    #pragma unroll
    for (int pair = 0; pair < 4; ++pair) {
        f32x4 w0, w1; int vm8, nqv, npv;
        switch (pair) {   // static after unroll (rule #20)
        case 0:  w0 = acc[0][0]; w1 = acc[0][1]; vm8 = (cb00 ? rown0 : 0) | (cb01 ? (rown0 << 4) : 0); nqv = nq[0]; npv = np_[0]; break;
        case 1:  w0 = acc[0][2]; w1 = acc[0][3]; vm8 = (cb10 ? rown0 : 0) | (cb11 ? (rown0 << 4) : 0); nqv = nq[0]; npv = np_[1]; break;
        case 2:  w0 = acc[1][0]; w1 = acc[1][1]; vm8 = (cb00 ? rown1 : 0) | (cb01 ? (rown1 << 4) : 0); nqv = nq[1]; npv = np_[0]; break;
        default: w0 = acc[1][2]; w1 = acc[1][3]; vm8 = (cb10 ? rown1 : 0) | (cb11 ? (rown1 << 4) : 0); nqv = nq[1]; npv = np_[1]; break;
        }

        int n  = nqv * npv;               // >= 1
        int k  = (4 * n) / 10; if (k < 1) k = 1;
        int m2 = n - (8 * n) / 10;        // complement rank, >= 1

        float v[8] = {w0[0], w0[1], w0[2], w0[3], w1[0], w1[1], w1[2], w1[3]};
        int key[8];
        float tot = 0.f;
        #pragma unroll
        for (int t = 0; t < 8; ++t) {
            int kf = (int)floorf(v[t] * 2.0f) + 512;     // monotone, |v| << 256
            kf = min(max(kf, 1), 1023);                  // v_med3_i32
            int msk = (vm8 << (31 - t)) >> 31;           // -1 if valid, else 0
            key[t] = kf & msk;                           // valid >= 1
            tot += __int_as_float(__float_as_int(v[t]) & msk);   // +0.0 if invalid
        }

        // dual 10-bit MSB-first radix descent — two formulations; unrolled
        // pairs interleave the SALU (ballot) and VALU (DPP) chains.
        int T1 = 0, T2 = 0;
        if ((pair & 1) == 0) {
            // ballot -> s_bcnt1_b64 (SALU); c1==c2 prefix shares counts
            for (int bit = 9; bit >= 0; --bit) {
                int c1 = T1 | (1 << bit);
                int c2 = T2 | (1 << bit);
                int cnt1 = 0;
                #pragma unroll
                for (int t = 0; t < 8; ++t)
                    cnt1 += __popcll(__ballot(key[t] >= c1));
                int cnt2;
                if (c2 == c1) {
                    cnt2 = cnt1;   // wave-uniform skip (identical count)
                } else {
                    cnt2 = 0;
                    #pragma unroll
                    for (int t = 0; t < 8; ++t)
                        cnt2 += __popcll(__ballot(key[t] >= c2));
                }
                if (cnt1 >= k)  T1 = c1;
                if (cnt2 >= m2) T2 = c2;
            }
        } else {
            // packed per-lane counts + DPP reduce + readlane (VALU pipe)
            for (int bit = 9; bit >= 0; --bit) {
                int c1 = T1 | (1 << bit);
                int c2 = T2 | (1 << bit);
                int cnt = 0;
                #pragma unroll
                for (int t = 0; t < 8; ++t) {
                    cnt += (key[t] >= c1) ? 1 : 0;
                    cnt += (key[t] >= c2) ? 0x10000 : 0;
                }
                cnt = dpp_reduce_i32(cnt);
                unsigned total = (unsigned)__builtin_amdgcn_readlane(cnt, 63);
                if ((int)(total & 0xFFFFu) >= k)  T1 = c1;
                if ((int)(total >> 16)    >= m2) T2 = c2;
            }
        }

        // tie-corrected sums (same formulation split for the counts)
        float S1 = 0.f, S2 = 0.f;
        int c1n, c2n;
        if ((pair & 1) == 0) {
            c1n = 0; c2n = 0;
            #pragma unroll
            for (int t = 0; t < 8; ++t) {
                bool g1 = key[t] > T1;
                bool g2 = key[t] > T2;
                if (g1) S1 += v[t];
                if (g2) S2 += v[t];
                c1n += __popcll(__ballot(g1));
                c2n += __popcll(__ballot(g2));
            }
        } else {
            int pc = 0;
            #pragma unroll
            for (int t = 0; t < 8; ++t) {
                if (key[t] > T1) { S1 += v[t]; pc += 1; }
                if (key[t] > T2) { S2 += v[t]; pc += 0x10000; }
            }
            pc = dpp_reduce_i32(pc);
            pc = __builtin_amdgcn_readlane(pc, 63);
            c1n = pc & 0xFFFF;
            c2n = (int)(((unsigned)pc) >> 16);
        }
        S1  = dpp_reduce_f32(S1);
        S2  = dpp_reduce_f32(S2);
        tot = dpp_reduce_f32(tot);

        if (lane == 63) {
            float f1 = 0.5f * (float)(T1 - 512);   // tie-bucket lower edge
            float f2 = 0.5f * (float)(T2 - 512);
            float top = S1 + (float)(k  - c1n) * f1;
            float cmp = S2 + (float)(m2 - c2n) * f2;
            float bot = tot - cmp;
            int bl = pair >> 1, pl = pair & 1;
            logits[(bBase + wr * 2 + bl) * PP + (pBase + wc * 2 + pl)] = aco * top - bco * bot;
        }
    }
}

// ---------- loss = mean_b (lse(logits[b,:]) - logits[b,b]) ----------
// 32 blocks x 4 waves, one row per wave, atomicAdd partials (out[0] zeroed
// by conv_fp8_both, stream-ordered).
__global__ __launch_bounds__(256) void loss_kernel(const float* __restrict__ logits,
                                                   float* __restrict__ loss_out) {
    const int lane = threadIdx.x & 63;
    const int wid  = threadIdx.x >> 6;
    const int r = blockIdx.x * 4 + wid;
    const float* row = logits + r * PP;
    float x0 = row[lane], x1 = row[lane + 64], x2 = row[lane + 128], x3 = row[lane + 192];
    float m = fmaxf(fmaxf(x0, x1), fmaxf(x2, x3));
    #pragma unroll
    for (int off = 32; off > 0; off >>= 1)
        m = fmaxf(m, __shfl_xor(m, off, 64));
    float s = expf(x0 - m) + expf(x1 - m) + expf(x2 - m) + expf(x3 - m);
    #pragma unroll
    for (int off = 32; off > 0; off >>= 1)
        s += __shfl_xor(s, off, 64);
    if (lane == 0)
        atomicAdd(loss_out, (m + logf(s) - row[r]) * (1.0f / (float)BQ));
}

extern "C" void kernel_launch(void* const* d_in, const int* in_sizes, int n_in,
                              void* d_out, int out_size, void* d_ws, size_t ws_size,
                              hipStream_t stream) {
    const float* q  = (const float*)d_in[0];
    const float* pe = (const float*)d_in[1];
    const int*   qm = (const int*)d_in[2];
    const int*   pm = (const int*)d_in[3];
    const float* ar = (const float*)d_in[4];
    const float* br = (const float*)d_in[5];
    float* out = (float*)d_out;           // [0] = loss, [1..32768] = logits

    // workspace: qb (1.5 MB fp8, k-shuffled) | pb (6 MB fp8, k-shuffled)
    char* ws = (char*)d_ws;
    unsigned char* qb = (unsigned char*)ws;
    unsigned char* pb = (unsigned char*)(ws + (size_t)MROWS * DD);

    // 1) convert fp32 -> fp8 e4m3 with k-shuffle (+ zero loss accumulator)
    conv_fp8_both<<<(NQG + NPG) / 256, 256, 0, stream>>>(
        (const float4*)q, (const float4*)pe, qb, pb, out);

    // 2) fused fp8 sim-GEMM + dual top-k -> logits
    // 36 KB ring-3 LDS; (256,4) -> 4 blocks/CU; counted vmcnt pipeline
    dim3 gg(NROWS / BN, MROWS / BM, 1);   // (64, 32) = 2048 blocks
    gemm_select<<<gg, 256, 0, stream>>>(qb, pb, qm, pm, ar, br, out + 1);

    // 3) loss (parallel, atomic accumulate)
    loss_kernel<<<32, 256, 0, stream>>>(out + 1, out);
}

// Round 14
// 132.515 us; speedup vs baseline: 1.1299x; 1.0200x over previous
//
#include <hip/hip_runtime.h>
#include <hip/hip_bf16.h>
#include <math.h>

// Problem constants
#define BQ 128
#define PP 256
#define MQ 16
#define MP 32
#define DD 768
#define MROWS (BQ*MQ)   // 2048
#define NROWS (PP*MP)   // 8192

typedef float f32x4 __attribute__((ext_vector_type(4)));
typedef int   i32x4 __attribute__((ext_vector_type(4)));

// ---------- fp32 -> fp8 e4m3 + k-shuffle, both tensors, one launch ----------
// Within each 64-k block, 16B chunk c holds k-groups {c, c+4}. One
// ds_read_b128 feeds TWO 16x16x32 MFMAs (k and k+32). Also zero-inits
// loss_out[0] (stream-ordered before loss_kernel).
#define NQG (MROWS*96)   // 196608 groups of 8
#define NPG (NROWS*96)   // 786432

__global__ void conv_fp8_both(const float4* __restrict__ q, const float4* __restrict__ p,
                              unsigned char* __restrict__ qb, unsigned char* __restrict__ pb,
                              float* __restrict__ loss_out) {
    int idx = blockIdx.x * blockDim.x + threadIdx.x;
    if (idx == 0) loss_out[0] = 0.f;
    const float4* in; unsigned char* out; int i;
    if (idx < NQG) { in = q; out = qb; i = idx; }
    else           { in = p; out = pb; i = idx - NQG; }
    float4 x0 = in[2 * i];
    float4 x1 = in[2 * i + 1];
    int lo = 0, hi = 0;
    lo = __builtin_amdgcn_cvt_pk_fp8_f32(x0.x, x0.y, lo, false);
    lo = __builtin_amdgcn_cvt_pk_fp8_f32(x0.z, x0.w, lo, true);
    hi = __builtin_amdgcn_cvt_pk_fp8_f32(x1.x, x1.y, hi, false);
    hi = __builtin_amdgcn_cvt_pk_fp8_f32(x1.z, x1.w, hi, true);
    int row = i / 96;
    int g96 = i - row * 96;
    int blk = g96 >> 3, g = g96 & 7;
    int dstoff = (g < 4) ? (g * 16) : ((g - 4) * 16 + 8);
    *(uint2*)(out + (size_t)row * DD + blk * 64 + dstoff) = make_uint2((unsigned)lo, (unsigned)hi);
}

// ---------- DPP wave-64 reductions (pure VALU) ----------
__device__ inline int dpp_reduce_i32(int v) {
    v += __builtin_amdgcn_update_dpp(0, v, 0x111, 0xF, 0xF, true);  // row_shr:1
    v += __builtin_amdgcn_update_dpp(0, v, 0x112, 0xF, 0xF, true);  // row_shr:2
    v += __builtin_amdgcn_update_dpp(0, v, 0x114, 0xF, 0xF, true);  // row_shr:4
    v += __builtin_amdgcn_update_dpp(0, v, 0x118, 0xF, 0xF, true);  // row_shr:8
    v += __builtin_amdgcn_update_dpp(0, v, 0x142, 0xA, 0xF, true);  // row_bcast:15
    v += __builtin_amdgcn_update_dpp(0, v, 0x143, 0xC, 0xF, true);  // row_bcast:31
    return v;   // lane 63 = total
}

__device__ inline float dpp_reduce_f32(float x) {
    int m;
    m = __builtin_amdgcn_update_dpp(0, __float_as_int(x), 0x111, 0xF, 0xF, true); x += __int_as_float(m);
    m = __builtin_amdgcn_update_dpp(0, __float_as_int(x), 0x112, 0xF, 0xF, true); x += __int_as_float(m);
    m = __builtin_amdgcn_update_dpp(0, __float_as_int(x), 0x114, 0xF, 0xF, true); x += __int_as_float(m);
    m = __builtin_amdgcn_update_dpp(0, __float_as_int(x), 0x118, 0xF, 0xF, true); x += __int_as_float(m);
    m = __builtin_amdgcn_update_dpp(0, __float_as_int(x), 0x142, 0xA, 0xF, true); x += __int_as_float(m);
    m = __builtin_amdgcn_update_dpp(0, __float_as_int(x), 0x143, 0xC, 0xF, true); x += __int_as_float(m);
    return x;   // lane 63 = total
}

// ---------- fused fp8 GEMM (64x128, ring-2, one barrier/iter) + select ------
// R14: combine the two proven pieces. R13 established (a) unrolled select
// is worth -2.4 us (latency-bound, ILP helps) and (b) actual reg need is 52
// VGPR — so R12's spills came from the (256,6) BUDGET, not the ring-2
// structure. The 6-blocks/CU cell is reachable via LESS LDS at (256,4):
//  - ring-2 (2 x 12 KB = 24 KB) -> 6 blocks/CU = 24 waves/CU; VGPR 52
//    (8-wave tier) no longer the cap; (256,4) budget 128 — no spills.
//  - R12's loop: wait vmcnt(0) each iter (own 3 loads, issued one full
//    iter ~250cy earlier), ONE barrier, stage t+1 into the vacated slot.
//  - select = R13 verbatim (fully unrolled, SALU/VALU split).
// WRITE_SIZE >= 2 MB = spilled -> experiment void, revert to R13.
// Accumulation order unchanged -> absmax must stay exactly 96.0.
#define BM 64
#define BN 128
#define BK 64
#define KIT (DD / BK)    // 12
#define SLOT 12288       // A 4 KB + B 8 KB

__device__ inline void load16_to_lds(const unsigned char* g, unsigned char* l) {
    __builtin_amdgcn_global_load_lds(
        (const __attribute__((address_space(1))) unsigned int*)(g),
        (__attribute__((address_space(3))) unsigned int*)(l),
        16, 0, 0);
}

__device__ inline unsigned lds_off(const unsigned char* p) {
    return (unsigned)(unsigned long long)
        (const __attribute__((address_space(3))) unsigned char*)p;
}

__device__ inline i32x4 ds_read_b128a(unsigned addr) {
    i32x4 d;
    asm volatile("ds_read_b128 %0, %1" : "=v"(d) : "v"(addr));
    return d;
}

__device__ inline float softplus_f(float x) {
    return (x > 20.f) ? x : log1pf(expf(x));
}

__device__ inline long lo64(i32x4 v) {
    return (long)(((unsigned long)(unsigned)v[1] << 32) | (unsigned)v[0]);
}
__device__ inline long hi64(i32x4 v) {
    return (long)(((unsigned long)(unsigned)v[3] << 32) | (unsigned)v[2]);
}

__global__ __launch_bounds__(256, 4) void gemm_select(const unsigned char* __restrict__ A,
                                                      const unsigned char* __restrict__ B,
                                                      const int* __restrict__ qm,
                                                      const int* __restrict__ pm,
                                                      const float* __restrict__ araw,
                                                      const float* __restrict__ braw,
                                                      float* __restrict__ logits) {
    __shared__ __align__(16) unsigned char smem[2 * SLOT];   // 24 KB ring-2

    const int tid  = threadIdx.x;
    const int lane = tid & 63;
    const int wid  = tid >> 6;        // 4 waves, 2x2 over 64x128
    const int wr   = wid >> 1;
    const int wc   = wid & 1;
    const int tileM = blockIdx.y * BM;
    const int tileN = blockIdx.x * BN;
    const int bBase = blockIdx.y * 4;
    const int pBase = blockIdx.x * 4;

    // ---- GEMM phase (fp8, BK=64, ring-2 one-barrier pipeline)
    f32x4 acc[2][4];
    #pragma unroll
    for (int i = 0; i < 2; ++i)
        #pragma unroll
        for (int j = 0; j < 4; ++j) {
            f32x4 z = {0.f, 0.f, 0.f, 0.f};
            acc[i][j] = z;
        }

    const int lr = lane >> 2, l2 = lane & 3;
    const int sg = (lr >> 1) & 3;                    // sigma(row): row%16 = lr
    const int rowA  = wid * 16 + lr;                 // A rows 0..63
    const int rowB0 = wid * 16 + lr;                 // B rows 0..63
    const int rowB1 = 64 + wid * 16 + lr;            // B rows 64..127
    const unsigned char* pa  = A + (size_t)(tileM + rowA ) * DD + ((l2 ^ sg) << 4);
    const unsigned char* pb0 = B + (size_t)(tileN + rowB0) * DD + ((l2 ^ sg) << 4);
    const unsigned char* pb1 = B + (size_t)(tileN + rowB1) * DD + ((l2 ^ sg) << 4);
    const int dA  = wid * 16 * BK;                   // wave-uniform, A region
    const int dB0 = 4096 + wid * 16 * BK;            // B region base 4096
    const int dB1 = 4096 + (4 + wid) * 16 * BK;

    const int r0 = lane & 15;
    const int q  = lane >> 4;
    const int slotq = ((q ^ ((r0 >> 1) & 3)) << 4);
    const int abase = (wr * 32 + r0) * BK + slotq;          // + mi*16*BK
    const int bbase = 4096 + (wc * 64 + r0) * BK + slotq;   // + ni*16*BK
    const unsigned lds0 = lds_off(smem);

    // prologue: stage K-tile 0 into slot 0 (3 loads outstanding)
    load16_to_lds(pa,  smem + dA);
    load16_to_lds(pb0, smem + dB0);
    load16_to_lds(pb1, smem + dB1);
    pa += BK; pb0 += BK; pb1 += BK;

    #pragma unroll
    for (int t = 0; t < KIT; ++t) {
        // tile t's 3 loads were issued one full iteration ago; drain them.
        asm volatile("s_waitcnt vmcnt(0)" ::: "memory");
        __builtin_amdgcn_s_barrier();   // t's data visible; t-1 reads done

        if (t + 1 < KIT) {   // stage t+1 into the slot t-1 just vacated
            unsigned char* sb = smem + ((t + 1) & 1) * SLOT;
            load16_to_lds(pa,  sb + dA);
            load16_to_lds(pb0, sb + dB0);
            load16_to_lds(pb1, sb + dB1);
            pa += BK; pb0 += BK; pb1 += BK;
        }

        const unsigned sb = lds0 + (unsigned)((t & 1) * SLOT);
        i32x4 a0 = ds_read_b128a(sb + abase);
        i32x4 a1 = ds_read_b128a(sb + abase + 16 * BK);
        i32x4 b0 = ds_read_b128a(sb + bbase);
        i32x4 b1 = ds_read_b128a(sb + bbase + 16 * BK);
        i32x4 b2 = ds_read_b128a(sb + bbase + 32 * BK);
        i32x4 b3 = ds_read_b128a(sb + bbase + 48 * BK);
        asm volatile("s_waitcnt lgkmcnt(0)" ::: "memory");
        __builtin_amdgcn_sched_barrier(0);   // rule #18: pin MFMAs below wait

        acc[0][0] = __builtin_amdgcn_mfma_f32_16x16x32_fp8_fp8(lo64(a0), lo64(b0), acc[0][0], 0, 0, 0);
        acc[0][1] = __builtin_amdgcn_mfma_f32_16x16x32_fp8_fp8(lo64(a0), lo64(b1), acc[0][1], 0, 0, 0);
        acc[0][2] = __builtin_amdgcn_mfma_f32_16x16x32_fp8_fp8(lo64(a0), lo64(b2), acc[0][2], 0, 0, 0);
        acc[0][3] = __builtin_amdgcn_mfma_f32_16x16x32_fp8_fp8(lo64(a0), lo64(b3), acc[0][3], 0, 0, 0);
        acc[1][0] = __builtin_amdgcn_mfma_f32_16x16x32_fp8_fp8(lo64(a1), lo64(b0), acc[1][0], 0, 0, 0);
        acc[1][1] = __builtin_amdgcn_mfma_f32_16x16x32_fp8_fp8(lo64(a1), lo64(b1), acc[1][1], 0, 0, 0);
        acc[1][2] = __builtin_amdgcn_mfma_f32_16x16x32_fp8_fp8(lo64(a1), lo64(b2), acc[1][2], 0, 0, 0);
        acc[1][3] = __builtin_amdgcn_mfma_f32_16x16x32_fp8_fp8(lo64(a1), lo64(b3), acc[1][3], 0, 0, 0);
        acc[0][0] = __builtin_amdgcn_mfma_f32_16x16x32_fp8_fp8(hi64(a0), hi64(b0), acc[0][0], 0, 0, 0);
        acc[0][1] = __builtin_amdgcn_mfma_f32_16x16x32_fp8_fp8(hi64(a0), hi64(b1), acc[0][1], 0, 0, 0);
        acc[0][2] = __builtin_amdgcn_mfma_f32_16x16x32_fp8_fp8(hi64(a0), hi64(b2), acc[0][2], 0, 0, 0);
        acc[0][3] = __builtin_amdgcn_mfma_f32_16x16x32_fp8_fp8(hi64(a0), hi64(b3), acc[0][3], 0, 0, 0);
        acc[1][0] = __builtin_amdgcn_mfma_f32_16x16x32_fp8_fp8(hi64(a1), hi64(b0), acc[1][0], 0, 0, 0);
        acc[1][1] = __builtin_amdgcn_mfma_f32_16x16x32_fp8_fp8(hi64(a1), hi64(b1), acc[1][1], 0, 0, 0);
        acc[1][2] = __builtin_amdgcn_mfma_f32_16x16x32_fp8_fp8(hi64(a1), hi64(b2), acc[1][2], 0, 0, 0);
        acc[1][3] = __builtin_amdgcn_mfma_f32_16x16x32_fp8_fp8(hi64(a1), hi64(b3), acc[1][3], 0, 0, 0);
    }

    // ---- per-wave mask words (after K-loop: not live across it)
    unsigned qw[2]; int nq[2];
    #pragma unroll
    for (int t = 0; t < 2; ++t) {
        bool v = (lane < MQ) && (qm[(bBase + wr * 2 + t) * MQ + lane] != 0);
        unsigned long long bal = __ballot(v);
        qw[t] = (unsigned)bal;
        nq[t] = __popcll(bal);
    }
    unsigned pw[2]; int np_[2];
    #pragma unroll
    for (int t = 0; t < 2; ++t) {
        bool v = (lane < MP) && (pm[(pBase + wc * 2 + t) * MP + lane] != 0);
        unsigned long long bal = __ballot(v);
        pw[t] = (unsigned)bal;
        np_[t] = __popcll(bal);
    }

    // ---- selection: 4 pairs/wave, FULLY UNROLLED (R13 verbatim)
    // C/D layout (m89): row=(lane>>4)*4+(t&3), col=(t>>2)*16+(lane&15)
    float aco = softplus_f(araw[0]);
    float bco = softplus_f(braw[0]);
    const int rowb = (lane >> 4) * 4;
    const int colb = lane & 15;

    // per-lane validity precompute
    const int rown0 = (int)((qw[0] >> rowb) & 0xFu);
    const int rown1 = (int)((qw[1] >> rowb) & 0xFu);
    const int cb00 = (int)((pw[0] >> colb) & 1u);
    const int cb01 = (int)((pw[0] >> (colb + 16)) & 1u);
    const int cb10 = (int)((pw[1] >> colb) & 1u);
    const int cb11 = (int)((pw[1] >> (colb + 16)) & 1u);

    #pragma unroll
    for (int pair = 0; pair < 4; ++pair) {
        f32x4 w0, w1; int vm8, nqv, npv;
        switch (pair) {   // static after unroll (rule #20)
        case 0:  w0 = acc[0][0]; w1 = acc[0][1]; vm8 = (cb00 ? rown0 : 0) | (cb01 ? (rown0 << 4) : 0); nqv = nq[0]; npv = np_[0]; break;
        case 1:  w0 = acc[0][2]; w1 = acc[0][3]; vm8 = (cb10 ? rown0 : 0) | (cb11 ? (rown0 << 4) : 0); nqv = nq[0]; npv = np_[1]; break;
        case 2:  w0 = acc[1][0]; w1 = acc[1][1]; vm8 = (cb00 ? rown1 : 0) | (cb01 ? (rown1 << 4) : 0); nqv = nq[1]; npv = np_[0]; break;
        default: w0 = acc[1][2]; w1 = acc[1][3]; vm8 = (cb10 ? rown1 : 0) | (cb11 ? (rown1 << 4) : 0); nqv = nq[1]; npv = np_[1]; break;
        }

        int n  = nqv * npv;               // >= 1
        int k  = (4 * n) / 10; if (k < 1) k = 1;
        int m2 = n - (8 * n) / 10;        // complement rank, >= 1

        float v[8] = {w0[0], w0[1], w0[2], w0[3], w1[0], w1[1], w1[2], w1[3]};
        int key[8];
        float tot = 0.f;
        #pragma unroll
        for (int t = 0; t < 8; ++t) {
            int kf = (int)floorf(v[t] * 2.0f) + 512;     // monotone, |v| << 256
            kf = min(max(kf, 1), 1023);                  // v_med3_i32
            int msk = (vm8 << (31 - t)) >> 31;           // -1 if valid, else 0
            key[t] = kf & msk;                           // valid >= 1
            tot += __int_as_float(__float_as_int(v[t]) & msk);   // +0.0 if invalid
        }

        // dual 10-bit MSB-first radix descent — two formulations; unrolled
        // pairs interleave the SALU (ballot) and VALU (DPP) chains.
        int T1 = 0, T2 = 0;
        if ((pair & 1) == 0) {
            // ballot -> s_bcnt1_b64 (SALU); c1==c2 prefix shares counts
            for (int bit = 9; bit >= 0; --bit) {
                int c1 = T1 | (1 << bit);
                int c2 = T2 | (1 << bit);
                int cnt1 = 0;
                #pragma unroll
                for (int t = 0; t < 8; ++t)
                    cnt1 += __popcll(__ballot(key[t] >= c1));
                int cnt2;
                if (c2 == c1) {
                    cnt2 = cnt1;   // wave-uniform skip (identical count)
                } else {
                    cnt2 = 0;
                    #pragma unroll
                    for (int t = 0; t < 8; ++t)
                        cnt2 += __popcll(__ballot(key[t] >= c2));
                }
                if (cnt1 >= k)  T1 = c1;
                if (cnt2 >= m2) T2 = c2;
            }
        } else {
            // packed per-lane counts + DPP reduce + readlane (VALU pipe)
            for (int bit = 9; bit >= 0; --bit) {
                int c1 = T1 | (1 << bit);
                int c2 = T2 | (1 << bit);
                int cnt = 0;
                #pragma unroll
                for (int t = 0; t < 8; ++t) {
                    cnt += (key[t] >= c1) ? 1 : 0;
                    cnt += (key[t] >= c2) ? 0x10000 : 0;
                }
                cnt = dpp_reduce_i32(cnt);
                unsigned total = (unsigned)__builtin_amdgcn_readlane(cnt, 63);
                if ((int)(total & 0xFFFFu) >= k)  T1 = c1;
                if ((int)(total >> 16)    >= m2) T2 = c2;
            }
        }

        // tie-corrected sums (same formulation split for the counts)
        float S1 = 0.f, S2 = 0.f;
        int c1n, c2n;
        if ((pair & 1) == 0) {
            c1n = 0; c2n = 0;
            #pragma unroll
            for (int t = 0; t < 8; ++t) {
                bool g1 = key[t] > T1;
                bool g2 = key[t] > T2;
                if (g1) S1 += v[t];
                if (g2) S2 += v[t];
                c1n += __popcll(__ballot(g1));
                c2n += __popcll(__ballot(g2));
            }
        } else {
            int pc = 0;
            #pragma unroll
            for (int t = 0; t < 8; ++t) {
                if (key[t] > T1) { S1 += v[t]; pc += 1; }
                if (key[t] > T2) { S2 += v[t]; pc += 0x10000; }
            }
            pc = dpp_reduce_i32(pc);
            pc = __builtin_amdgcn_readlane(pc, 63);
            c1n = pc & 0xFFFF;
            c2n = (int)(((unsigned)pc) >> 16);
        }
        S1  = dpp_reduce_f32(S1);
        S2  = dpp_reduce_f32(S2);
        tot = dpp_reduce_f32(tot);

        if (lane == 63) {
            float f1 = 0.5f * (float)(T1 - 512);   // tie-bucket lower edge
            float f2 = 0.5f * (float)(T2 - 512);
            float top = S1 + (float)(k  - c1n) * f1;
            float cmp = S2 + (float)(m2 - c2n) * f2;
            float bot = tot - cmp;
            int bl = pair >> 1, pl = pair & 1;
            logits[(bBase + wr * 2 + bl) * PP + (pBase + wc * 2 + pl)] = aco * top - bco * bot;
        }
    }
}

// ---------- loss = mean_b (lse(logits[b,:]) - logits[b,b]) ----------
// 32 blocks x 4 waves, one row per wave, atomicAdd partials (out[0] zeroed
// by conv_fp8_both, stream-ordered).
__global__ __launch_bounds__(256) void loss_kernel(const float* __restrict__ logits,
                                                   float* __restrict__ loss_out) {
    const int lane = threadIdx.x & 63;
    const int wid  = threadIdx.x >> 6;
    const int r = blockIdx.x * 4 + wid;
    const float* row = logits + r * PP;
    float x0 = row[lane], x1 = row[lane + 64], x2 = row[lane + 128], x3 = row[lane + 192];
    float m = fmaxf(fmaxf(x0, x1), fmaxf(x2, x3));
    #pragma unroll
    for (int off = 32; off > 0; off >>= 1)
        m = fmaxf(m, __shfl_xor(m, off, 64));
    float s = expf(x0 - m) + expf(x1 - m) + expf(x2 - m) + expf(x3 - m);
    #pragma unroll
    for (int off = 32; off > 0; off >>= 1)
        s += __shfl_xor(s, off, 64);
    if (lane == 0)
        atomicAdd(loss_out, (m + logf(s) - row[r]) * (1.0f / (float)BQ));
}

extern "C" void kernel_launch(void* const* d_in, const int* in_sizes, int n_in,
                              void* d_out, int out_size, void* d_ws, size_t ws_size,
                              hipStream_t stream) {
    const float* q  = (const float*)d_in[0];
    const float* pe = (const float*)d_in[1];
    const int*   qm = (const int*)d_in[2];
    const int*   pm = (const int*)d_in[3];
    const float* ar = (const float*)d_in[4];
    const float* br = (const float*)d_in[5];
    float* out = (float*)d_out;           // [0] = loss, [1..32768] = logits

    // workspace: qb (1.5 MB fp8, k-shuffled) | pb (6 MB fp8, k-shuffled)
    char* ws = (char*)d_ws;
    unsigned char* qb = (unsigned char*)ws;
    unsigned char* pb = (unsigned char*)(ws + (size_t)MROWS * DD);

    // 1) convert fp32 -> fp8 e4m3 with k-shuffle (+ zero loss accumulator)
    conv_fp8_both<<<(NQG + NPG) / 256, 256, 0, stream>>>(
        (const float4*)q, (const float4*)pe, qb, pb, out);

    // 2) fused fp8 sim-GEMM + dual top-k -> logits
    // 24 KB ring-2 LDS at (256,4): 6 blocks/CU (LDS-capped), 128-reg
    // budget >> 52 needed -> no spills (the cell R12 missed)
    dim3 gg(NROWS / BN, MROWS / BM, 1);   // (64, 32) = 2048 blocks
    gemm_select<<<gg, 256, 0, stream>>>(qb, pb, qm, pm, ar, br, out + 1);

    // 3) loss (parallel, atomic accumulate)
    loss_kernel<<<32, 256, 0, stream>>>(out + 1, out);
}